// Round 2
// baseline (15633.705 us; speedup 1.0000x reference)
//
#include <hip/hip_runtime.h>
#include <math.h>

#define B    32
#define EMBD 1024
#define HID  1024
#define G    4096   // 4*HID
#define V    32000
#define TS   128
#define KSL  32     // k-splits for LSTM gates (chunk = 32)
#define KSF  8      // k-splits for FC (chunk = 128)

#define FMA4(acc, W_, V_) \
  acc = fmaf((W_).x,(V_).x, fmaf((W_).y,(V_).y, fmaf((W_).z,(V_).z, fmaf((W_).w,(V_).w,(acc)))))

// ---------------- init: cur_in = emb[x[:,0]], h=c=0 ----------------
__global__ __launch_bounds__(256) void k_init(
    const int* __restrict__ x, const float* __restrict__ emb,
    float* __restrict__ cur_in, float* __restrict__ h, float* __restrict__ c)
{
    const int b = blockIdx.x, tid = threadIdx.x;
    const int tok = x[b * (TS + 1)];
    const float4* src = (const float4*)(emb + (size_t)tok * EMBD);
    ((float4*)(cur_in + (size_t)b * EMBD))[tid] = src[tid];
    float4 z = {0.f, 0.f, 0.f, 0.f};
    ((float4*)(h + (size_t)b * HID))[tid] = z;
    ((float4*)(h + (size_t)B * HID + (size_t)b * HID))[tid] = z;
    ((float4*)(c + (size_t)b * HID))[tid] = z;
    ((float4*)(c + (size_t)B * HID + (size_t)b * HID))[tid] = z;
}

// ---------------- LSTM gates partial GEMM ----------------
// part[ks][b][j] = sum_{k in chunk} x[b][k]*Wih[j][k] + h[b][k]*Whh[j][k]
// grid (8, KSL), block 256. Each thread: 2 j's (tid, tid+256), all 32 b's.
__global__ __launch_bounds__(256) void k_gates(
    const float* __restrict__ xin, const float* __restrict__ hin,
    const float* __restrict__ Wih, const float* __restrict__ Whh,
    float* __restrict__ part)
{
    __shared__ float4 xs[B][8];
    __shared__ float4 hs[B][8];
    const int tid = threadIdx.x;
    const int bj = blockIdx.x;      // 0..7
    const int ks = blockIdx.y;      // 0..KSL-1
    const int kbase = ks * (EMBD / KSL);   // *32
    {
        const int b = tid >> 3, kk = tid & 7;
        xs[b][kk] = *(const float4*)(xin + (size_t)b * EMBD + kbase + kk * 4);
        hs[b][kk] = *(const float4*)(hin + (size_t)b * HID + kbase + kk * 4);
    }
    __syncthreads();

    const int j0 = bj * 512 + tid;
    const int j1 = j0 + 256;
    const float* wi0 = Wih + (size_t)j0 * EMBD + kbase;
    const float* wi1 = Wih + (size_t)j1 * EMBD + kbase;
    const float* wh0 = Whh + (size_t)j0 * HID + kbase;
    const float* wh1 = Whh + (size_t)j1 * HID + kbase;

    float acc0[B], acc1[B];
#pragma unroll
    for (int b = 0; b < B; b++) { acc0[b] = 0.f; acc1[b] = 0.f; }

#pragma unroll 2
    for (int kk = 0; kk < 8; kk++) {
        float4 a0 = *(const float4*)(wi0 + kk * 4);
        float4 a1 = *(const float4*)(wi1 + kk * 4);
        float4 c0 = *(const float4*)(wh0 + kk * 4);
        float4 c1 = *(const float4*)(wh1 + kk * 4);
#pragma unroll
        for (int b = 0; b < B; b++) {
            float4 xv = xs[b][kk];
            float4 hv = hs[b][kk];
            FMA4(acc0[b], a0, xv);
            FMA4(acc0[b], c0, hv);
            FMA4(acc1[b], a1, xv);
            FMA4(acc1[b], c1, hv);
        }
    }
#pragma unroll
    for (int b = 0; b < B; b++) {
        part[((size_t)ks * B + b) * G + j0] = acc0[b];
        part[((size_t)ks * B + b) * G + j1] = acc1[b];
    }
}

// ---------------- reduce partials + activations + state update ----------------
// grid 128, block 256; idx = b*1024 + jh
__global__ __launch_bounds__(256) void k_act(
    const float* __restrict__ part, const float* __restrict__ bih,
    const float* __restrict__ bhh, float* __restrict__ c, float* __restrict__ h)
{
    const int idx = blockIdx.x * 256 + threadIdx.x;
    const int b = idx >> 10, jh = idx & 1023;
    float gi = bih[jh]        + bhh[jh];
    float gf = bih[jh + 1024] + bhh[jh + 1024];
    float gg = bih[jh + 2048] + bhh[jh + 2048];
    float go = bih[jh + 3072] + bhh[jh + 3072];
    for (int ks = 0; ks < KSL; ks++) {
        const float* p = part + ((size_t)ks * B + b) * G;
        gi += p[jh]; gf += p[jh + 1024]; gg += p[jh + 2048]; go += p[jh + 3072];
    }
    const float i = 1.f / (1.f + expf(-gi));
    const float f = 1.f / (1.f + expf(-gf));
    const float g = tanhf(gg);
    const float o = 1.f / (1.f + expf(-go));
    const float cn = f * c[idx] + i * g;
    c[idx] = cn;
    h[idx] = o * tanhf(cn);
}

// ---------------- FC partial GEMM ----------------
// part[ks][b][j] = sum_{k in chunk} h[b][k]*Wfc[j][k]
// grid (32, KSF), block 256. Each thread: 4 j's, all 32 b's.
__global__ __launch_bounds__(256) void k_fc(
    const float* __restrict__ hin, const float* __restrict__ W,
    float* __restrict__ part)
{
    __shared__ float4 xs[B][32];
    const int tid = threadIdx.x;
    const int bj = blockIdx.x;      // 0..31
    const int ks = blockIdx.y;      // 0..KSF-1
    const int kbase = ks * (HID / KSF);    // *128
#pragma unroll
    for (int q = 0; q < 4; q++) {
        const int idx = q * 256 + tid;
        const int b = idx >> 5, kk = idx & 31;
        xs[b][kk] = *(const float4*)(hin + (size_t)b * HID + kbase + kk * 4);
    }
    __syncthreads();

    int jq[4]; bool vq[4]; const float* wp[4];
#pragma unroll
    for (int q = 0; q < 4; q++) {
        jq[q] = bj * 1024 + q * 256 + tid;
        vq[q] = (jq[q] < V);
        const int jc = vq[q] ? jq[q] : (V - 1);
        wp[q] = W + (size_t)jc * HID + kbase;
    }

    float acc[4][B];
#pragma unroll
    for (int q = 0; q < 4; q++)
#pragma unroll
        for (int b = 0; b < B; b++) acc[q][b] = 0.f;

#pragma unroll 2
    for (int kk = 0; kk < 32; kk++) {
        float4 w0 = *(const float4*)(wp[0] + kk * 4);
        float4 w1 = *(const float4*)(wp[1] + kk * 4);
        float4 w2 = *(const float4*)(wp[2] + kk * 4);
        float4 w3 = *(const float4*)(wp[3] + kk * 4);
#pragma unroll
        for (int b = 0; b < B; b++) {
            float4 xv = xs[b][kk];
            FMA4(acc[0][b], w0, xv);
            FMA4(acc[1][b], w1, xv);
            FMA4(acc[2][b], w2, xv);
            FMA4(acc[3][b], w3, xv);
        }
    }
#pragma unroll
    for (int q = 0; q < 4; q++) {
        if (vq[q]) {
#pragma unroll
            for (int b = 0; b < B; b++)
                part[((size_t)ks * B + b) * V + jq[q]] = acc[q][b];
        }
    }
}

// ---------------- FC reduce + exp-sum + argmax partials ----------------
// grid (16 chunks, 32 b), block 256. chunk covers 2000 vocab entries.
__global__ __launch_bounds__(256) void k_fcred(
    const float* __restrict__ part, const float* __restrict__ bfc,
    float* __restrict__ rsum, float* __restrict__ rmax, int* __restrict__ ridx)
{
    const int ch = blockIdx.x;   // 0..15
    const int b  = blockIdx.y;   // 0..31
    const int tid = threadIdx.x;
    float lsum = 0.f, lmax = -1e30f; int li = 0;
    for (int it = 0; it < 8; it++) {
        const int jj = it * 256 + tid;
        if (jj < 2000) {
            const int j = ch * 2000 + jj;
            float l = bfc[j];
#pragma unroll
            for (int ks = 0; ks < KSF; ks++)
                l += part[((size_t)ks * B + b) * V + j];
            lsum += expf(l);
            if (l > lmax) { lmax = l; li = j; }
        }
    }
    __shared__ float ssum[256], smax[256];
    __shared__ int sidx[256];
    ssum[tid] = lsum; smax[tid] = lmax; sidx[tid] = li;
    __syncthreads();
    for (int s = 128; s > 0; s >>= 1) {
        if (tid < s) {
            ssum[tid] += ssum[tid + s];
            const float mv = smax[tid + s]; const int mi = sidx[tid + s];
            if (mv > smax[tid] || (mv == smax[tid] && mi < sidx[tid])) {
                smax[tid] = mv; sidx[tid] = mi;
            }
        }
        __syncthreads();
    }
    if (tid == 0) {
        const int o = b * 16 + ch;
        rsum[o] = ssum[0]; rmax[o] = smax[0]; ridx[o] = sidx[0];
    }
}

// ---------------- finalize: p, argmax, next input embedding ----------------
// grid 32 (b), block 256
__global__ __launch_bounds__(256) void k_fin(
    const float* __restrict__ part, const float* __restrict__ bfc,
    const float* __restrict__ rsum, const float* __restrict__ rmax,
    const int* __restrict__ ridx, const int* __restrict__ x,
    const float* __restrict__ emb, float* __restrict__ cur_in,
    float* __restrict__ out, int t)
{
    const int b = blockIdx.x, tid = threadIdx.x;
    __shared__ int s_pred;
    if (tid == 0) {
        float tot = 0.f, bm = -1e30f; int bi = 0;
        for (int ch = 0; ch < 16; ch++) {
            const int o = b * 16 + ch;
            tot += rsum[o];
            const float mv = rmax[o]; const int mi = ridx[o];
            if (mv > bm || (mv == bm && mi < bi)) { bm = mv; bi = mi; }
        }
        const int tgt = x[b * (TS + 1) + t + 1];
        float lt = bfc[tgt];
        for (int ks = 0; ks < KSF; ks++)
            lt += part[((size_t)ks * B + b) * V + tgt];
        out[(size_t)b * TS + t] = expf(lt) / tot;
        s_pred = bi;
    }
    __syncthreads();
    const float4* src = (const float4*)(emb + (size_t)s_pred * EMBD);
    ((float4*)(cur_in + (size_t)b * EMBD))[tid] = src[tid];
}

extern "C" void kernel_launch(void* const* d_in, const int* in_sizes, int n_in,
                              void* d_out, int out_size, void* d_ws, size_t ws_size,
                              hipStream_t stream)
{
    const int*   x   = (const int*)  d_in[0];
    const float* emb = (const float*)d_in[1];
    const float* Wih = (const float*)d_in[2];
    const float* Whh = (const float*)d_in[3];
    const float* bih = (const float*)d_in[4];
    const float* bhh = (const float*)d_in[5];
    const float* Wfc = (const float*)d_in[6];
    const float* bfc = (const float*)d_in[7];
    float* out = (float*)d_out;

    float* ws = (float*)d_ws;
    float* cur_in = ws;                               // B*EMBD
    float* h      = cur_in + (size_t)B * EMBD;        // 2*B*HID
    float* c      = h + 2 * (size_t)B * HID;          // 2*B*HID
    float* gpart  = c + 2 * (size_t)B * HID;          // KSL*B*G
    float* fpart  = gpart + (size_t)KSL * B * G;      // KSF*B*V
    float* rsum   = fpart + (size_t)KSF * B * V;      // 512
    float* rmax   = rsum + 512;                       // 512
    int*   ridx   = (int*)(rmax + 512);               // 512

    k_init<<<B, 256, 0, stream>>>(x, emb, cur_in, h, c);

    for (int t = 0; t < TS; t++) {
        // layer 0
        k_gates<<<dim3(8, KSL), 256, 0, stream>>>(cur_in, h, Wih, Whh, gpart);
        k_act<<<128, 256, 0, stream>>>(gpart, bih, bhh, c, h);
        // layer 1 (input = layer0 h)
        k_gates<<<dim3(8, KSL), 256, 0, stream>>>(h, h + (size_t)B * HID,
                                                  Wih + (size_t)G * EMBD,
                                                  Whh + (size_t)G * HID, gpart);
        k_act<<<128, 256, 0, stream>>>(gpart, bih + G, bhh + G,
                                       c + (size_t)B * HID, h + (size_t)B * HID);
        // FC + softmax + argmax + next input
        k_fc<<<dim3(32, KSF), 256, 0, stream>>>(h + (size_t)B * HID, Wfc, fpart);
        k_fcred<<<dim3(16, B), 256, 0, stream>>>(fpart, bfc, rsum, rmax, ridx);
        k_fin<<<B, 256, 0, stream>>>(fpart, bfc, rsum, rmax, ridx, x, emb,
                                     cur_in, out, t);
    }
}